// Round 5
// baseline (409.779 us; speedup 1.0000x reference)
//
#include <hip/hip_runtime.h>

// SOBA-Monarch, B*H=64 heads, S=4096, D=64, nb=bs=64, pad=0, 3 steps.
// Round 5: 4 tiles/WG with register prefetch (grid 1024, all co-resident),
// f32 intermediates (split-to-bf16 at consume time only), producer-contiguous
// alpha/tau. Layouts: G [h][j][k][v] | Hm,Y [h][k][j][v] | M [h][j][v] (f32)
//                     alpha [h][k][j] | tau [h][j][k]

namespace {

typedef __attribute__((ext_vector_type(8))) short short8v;
typedef __attribute__((ext_vector_type(4))) float f32x4;

constexpr int HEADS = 64;
constexpr size_t HEADQ = 262144;                 // 4096*64 per head
constexpr size_t MATF  = (size_t)HEADS * 262144;

#define MFMA(ACC, A, B) ACC = __builtin_amdgcn_mfma_f32_16x16x32_bf16(A, B, ACC, 0, 0, 0)
#define LD8(arr, row, g8) (*(const short8v*)((arr) + (row) * 72 + (g8) * 8))

__device__ __forceinline__ float rmax16(float m) {
    m = fmaxf(m, __shfl_xor(m, 1));
    m = fmaxf(m, __shfl_xor(m, 2));
    m = fmaxf(m, __shfl_xor(m, 4));
    m = fmaxf(m, __shfl_xor(m, 8));
    return m;
}
__device__ __forceinline__ float rsum16(float s) {
    s += __shfl_xor(s, 1);
    s += __shfl_xor(s, 2);
    s += __shfl_xor(s, 4);
    s += __shfl_xor(s, 8);
    return s;
}

__device__ __forceinline__ void bfsplit(float x, ushort& h, ushort& l) {
    uint u = __float_as_uint(x);
    uint hi = (u + 0x7FFFu + ((u >> 16) & 1u)) & 0xFFFF0000u;
    h = (ushort)(hi >> 16);
    l = (ushort)(__float_as_uint(x - __uint_as_float(hi)) >> 16);
}

struct Raw16  { float4 a, b, c, d; };
struct Frag16 { short8v h0, h1, l0, l1; };

__device__ __forceinline__ Raw16 raw_load(const float* p) {
    Raw16 r;
    r.a = *(const float4*)(p);
    r.b = *(const float4*)(p + 4);
    r.c = *(const float4*)(p + 8);
    r.d = *(const float4*)(p + 12);
    return r;
}
__device__ __forceinline__ Frag16 split16(const Raw16& r, float s) {
    float v[16] = {r.a.x*s, r.a.y*s, r.a.z*s, r.a.w*s, r.b.x*s, r.b.y*s, r.b.z*s, r.b.w*s,
                   r.c.x*s, r.c.y*s, r.c.z*s, r.c.w*s, r.d.x*s, r.d.y*s, r.d.z*s, r.d.w*s};
    Frag16 f;
    #pragma unroll
    for (int e = 0; e < 16; ++e) {
        ushort hh, ll; bfsplit(v[e], hh, ll);
        if (e < 8) { f.h0[e] = (short)hh; f.l0[e] = (short)ll; }
        else       { f.h1[e - 8] = (short)hh; f.l1[e - 8] = (short)ll; }
    }
    return f;
}
__device__ __forceinline__ void store_rows(ushort* H, ushort* L, int r, int c0,
                                           const Frag16& f) {
    *(short8v*)(H + r * 72 + c0)     = f.h0;
    *(short8v*)(H + r * 72 + c0 + 8) = f.h1;
    *(short8v*)(L + r * 72 + c0)     = f.l0;
    *(short8v*)(L + r * 72 + c0 + 8) = f.l1;
}
__device__ __forceinline__ void scatter_tr(ushort* H, ushort* L, int r, int c0,
                                           const Frag16& f) {
    #pragma unroll
    for (int e = 0; e < 8; ++e) {
        H[(c0 + e) * 72 + r] = (ushort)f.h0[e];
        L[(c0 + e) * 72 + r] = (ushort)f.l0[e];
    }
    #pragma unroll
    for (int e = 0; e < 8; ++e) {
        H[(c0 + 8 + e) * 72 + r] = (ushort)f.h1[e];
        L[(c0 + 8 + e) * 72 + r] = (ushort)f.l1[e];
    }
}

// staged [64][68] f32 tile -> contiguous 16KB global block
__device__ __forceinline__ void flush_f32(const float* OS, float* g, int tid) {
    #pragma unroll
    for (int q = 0; q < 4; ++q) {
        const int off = tid * 4 + q * 1024;
        float4 v = *(const float4*)(OS + (off >> 6) * 68 + (off & 63));
        *(float4*)(g + off) = v;
    }
}

__device__ __forceinline__ void mmstep(const ushort* AH, const ushort* AL,
                                       const ushort* BH, const ushort* BL,
                                       int w, int lo4, int hi4, f32x4 acc[4]) {
    #pragma unroll
    for (int ks = 0; ks < 2; ++ks) {
        short8v ah = LD8(AH, 16 * w + lo4, hi4 + 4 * ks);
        short8v al = LD8(AL, 16 * w + lo4, hi4 + 4 * ks);
        #pragma unroll
        for (int t = 0; t < 4; ++t) {
            short8v bh = LD8(BH, 16 * t + lo4, hi4 + 4 * ks);
            short8v bl = LD8(BL, 16 * t + lo4, hi4 + 4 * ks);
            MFMA(acc[t], ah, bh); MFMA(acc[t], ah, bl); MFMA(acc[t], al, bh);
        }
    }
}

// M[h][j][v] = (1/512) * sum_l Q[h][l*64+j][v]
__global__ __launch_bounds__(256) void kmean_kernel(const float* __restrict__ Q,
                                                    float* __restrict__ M) {
    const int wg = blockIdx.x;                     // 1024 WGs
    const int h  = wg >> 4;
    const int j  = ((wg & 15) << 2) + (threadIdx.x >> 6);
    const int v  = threadIdx.x & 63;
    const float* base = Q + (size_t)h * HEADQ + (size_t)j * 64 + v;
    float acc = 0.f;
    #pragma unroll
    for (int l = 0; l < 64; ++l) acc += base[(size_t)l * 4096];
    M[((size_t)h * 64 + j) * 64 + v] = acc * (1.0f / 512.0f);
}

// One WG per (h, k0..k0+3).
// MM1: beta[j,i]=sum_v G[j,v]K[i,v]; right=softmax_i(beta/tau); alpha[j]=sum r log r
// MM2: Hm[j,v]=sum_i right[j,i]K[i,v];  LAST: Y[j,v]=sum_i right[j,i]V[i,v]
template<int FIRST, int LAST>
__global__ __launch_bounds__(256, 4) void bc_kernel(
    const float* __restrict__ Gsrc,   // FIRST ? M[h][j][v] : G[h][j][k][v]
    const float* __restrict__ Kmat,
    const float* __restrict__ Vmat,   // LAST only
    const float* __restrict__ tauIn,  // !FIRST only, [h][j][k]
    float* __restrict__ HmOut,        // [h][k][j][v]
    float* __restrict__ alphaOut,     // [h][k][j]
    float* __restrict__ Yout)         // LAST only, [h][k][j][v]
{
    __shared__ uint SM[9216];                       // 36864 B -> 4 WG/CU
    ushort* Ah = (ushort*)SM;          ushort* Al = Ah + 4608;
    ushort* Bh = (ushort*)(SM + 4608); ushort* Bl = Bh + 4608;
    float* OSB = (float*)(SM + 4608);
    float* OSA = (float*)SM;

    const int wg = blockIdx.x, h = wg >> 4, k0 = (wg & 15) << 2;
    const int tid = threadIdx.x, r = tid & 63, c0 = (tid >> 6) << 4;
    const int w = tid >> 6, lo4 = tid & 15, hi4 = (tid >> 4) & 3;

    Raw16 nG = raw_load(FIRST ? Gsrc + ((size_t)h * 64 + r) * 64 + c0
                              : Gsrc + ((size_t)h * 64 + r) * 4096 + (size_t)k0 * 64 + c0);
    Raw16 nK = raw_load(Kmat + (size_t)h * HEADQ + (size_t)k0 * 4096 + r * 64 + c0);

    for (int t = 0; t < 4; ++t) {
        const int k = k0 + t;
        float tvv[4];
        #pragma unroll
        for (int rr = 0; rr < 4; ++rr)
            tvv[rr] = FIRST ? 1.f
                : tauIn[((size_t)h * 64 + 16 * w + 4 * hi4 + rr) * 64 + k];

        store_rows(Ah, Al, r, c0, split16(nG, 1.f));
        Frag16 fk = split16(nK, 1.f);
        store_rows(Bh, Bl, r, c0, fk);
        Raw16 rawV;
        if (LAST)
            rawV = raw_load(Vmat + (size_t)h * HEADQ + (size_t)k * 4096 + r * 64 + c0);
        if (t < 3) {     // prefetch next tile
            nG = raw_load(FIRST ? Gsrc + ((size_t)h * 64 + r) * 64 + c0
                                : Gsrc + ((size_t)h * 64 + r) * 4096 + (size_t)(k + 1) * 64 + c0);
            nK = raw_load(Kmat + (size_t)h * HEADQ + (size_t)(k + 1) * 4096 + r * 64 + c0);
        }
        __syncthreads();

        f32x4 acc[4] = {};
        mmstep(Ah, Al, Bh, Bl, w, lo4, hi4, acc);       // D[j,i]
        __syncthreads();

        // softmax over i; right -> A rows; K^T -> B
        #pragma unroll
        for (int rr = 0; rr < 4; ++rr) {
            const int j = 16 * w + 4 * hi4 + rr;
            const bool tz = !(tvv[rr] > 1e-8f);
            const float tvi = tz ? 1.f : 1.f / tvv[rr];
            float lg[4];
            #pragma unroll
            for (int tt = 0; tt < 4; ++tt) lg[tt] = acc[tt][rr] * tvi;
            float m = rmax16(fmaxf(fmaxf(lg[0], lg[1]), fmaxf(lg[2], lg[3])));
            float e[4], s = 0.f;
            #pragma unroll
            for (int tt = 0; tt < 4; ++tt) { e[tt] = __expf(lg[tt] - m); s += e[tt]; }
            s = rsum16(s);
            const float inv = 1.f / s;
            float ap = 0.f;
            #pragma unroll
            for (int tt = 0; tt < 4; ++tt) {
                const float rv = tz ? (1.f / 64.f) : e[tt] * inv;
                ap += (rv > 0.f) ? rv * __logf(rv) : 0.f;
                ushort hh, ll; bfsplit(rv, hh, ll);
                Ah[j * 72 + 16 * tt + lo4] = hh;
                Al[j * 72 + 16 * tt + lo4] = ll;
            }
            ap = rsum16(ap);
            if (lo4 == 0) alphaOut[((size_t)h * 64 + k) * 64 + j] = ap;
        }
        scatter_tr(Bh, Bl, r, c0, fk);                  // K^T over dead K rows
        __syncthreads();

        f32x4 acc2[4] = {};
        mmstep(Ah, Al, Bh, Bl, w, lo4, hi4, acc2);      // Hm: A=right, B=K^T
        f32x4 acc3[4] = {};
        if (LAST) {
            __syncthreads();
            scatter_tr(Bh, Bl, r, c0, split16(rawV, 1.f));
            __syncthreads();
            mmstep(Ah, Al, Bh, Bl, w, lo4, hi4, acc3);  // Y: A=right, B=V^T
        }
        __syncthreads();

        #pragma unroll
        for (int rr = 0; rr < 4; ++rr) {
            const int j = 16 * w + 4 * hi4 + rr;
            #pragma unroll
            for (int tt = 0; tt < 4; ++tt) {
                OSB[j * 68 + 16 * tt + lo4] = acc2[tt][rr];
                if (LAST) OSA[j * 68 + 16 * tt + lo4] = acc3[tt][rr];
            }
        }
        __syncthreads();
        flush_f32(OSB, HmOut + ((size_t)h * 64 + k) * 4096, tid);
        if (LAST) flush_f32(OSA, Yout + ((size_t)h * 64 + k) * 4096, tid);
        __syncthreads();                                // LDS free for next tile
    }
}

// One WG per (h, j0..j0+3).
// MM1: beta2[l,k]=sum_v q[l,v]Hm[k,v]; left=softmax_k(beta2-alpha[k])
// !LAST: G[k,v]=sum_l left[l,k]q[l,v]; tau[k] via ones-MFMA
//  LAST: Z[l,v]=sum_k left[l,k]Y[k,v]
template<int LAST>
__global__ __launch_bounds__(256, 4) void da_kernel(
    const float* __restrict__ Q,
    const float* __restrict__ HmIn,   // [h][k][j][v]
    const float* __restrict__ alphaIn,// [h][k][j]
    const float* __restrict__ Yin,    // LAST only, [h][k][j][v]
    float* __restrict__ Gout,         // !LAST, [h][j][k][v]
    float* __restrict__ tauOut,       // !LAST, [h][j][k]
    float* __restrict__ Zout)         // LAST
{
    __shared__ uint SM[9216];
    ushort* Ah = (ushort*)SM;          ushort* Al = Ah + 4608;
    ushort* Bh = (ushort*)(SM + 4608); ushort* Bl = Bh + 4608;
    float* OSB = (float*)(SM + 4608);

    const int wg = blockIdx.x, h = wg >> 4, j0 = (wg & 15) << 2;
    const int tid = threadIdx.x, r = tid & 63, c0 = (tid >> 6) << 4;
    const int w = tid >> 6, lo4 = tid & 15, hi4 = (tid >> 4) & 3;

    Raw16 nQ = raw_load(Q + (size_t)h * HEADQ + (size_t)r * 4096 + (size_t)j0 * 64 + c0);
    Raw16 nH = raw_load(HmIn + ((size_t)h * 64 + r) * 4096 + (size_t)j0 * 64 + c0);

    for (int t = 0; t < 4; ++t) {
        const int j = j0 + t;
        float av[4];
        #pragma unroll
        for (int tt = 0; tt < 4; ++tt)
            av[tt] = alphaIn[((size_t)h * 64 + 16 * tt + lo4) * 64 + j];

        Frag16 fq = split16(nQ, 0.125f);
        store_rows(Ah, Al, r, c0, fq);
        store_rows(Bh, Bl, r, c0, split16(nH, 1.f));
        Raw16 rawY;
        if (LAST)
            rawY = raw_load(Yin + ((size_t)h * 64 + r) * 4096 + (size_t)j * 64 + c0);
        if (t < 3) {
            nQ = raw_load(Q + (size_t)h * HEADQ + (size_t)r * 4096 + (size_t)(j + 1) * 64 + c0);
            nH = raw_load(HmIn + ((size_t)h * 64 + r) * 4096 + (size_t)(j + 1) * 64 + c0);
        }
        __syncthreads();

        f32x4 acc[4] = {};
        mmstep(Ah, Al, Bh, Bl, w, lo4, hi4, acc);       // D[l,k]
        __syncthreads();

        // left = softmax over k; left(^T) -> B; q^T / Y^T -> A
        #pragma unroll
        for (int rr = 0; rr < 4; ++rr) {
            const int l = 16 * w + 4 * hi4 + rr;
            float lg[4];
            #pragma unroll
            for (int tt = 0; tt < 4; ++tt) lg[tt] = acc[tt][rr] - av[tt];
            float m = rmax16(fmaxf(fmaxf(lg[0], lg[1]), fmaxf(lg[2], lg[3])));
            float e[4], s = 0.f;
            #pragma unroll
            for (int tt = 0; tt < 4; ++tt) { e[tt] = __expf(lg[tt] - m); s += e[tt]; }
            s = rsum16(s);
            const float inv = 1.f / s;
            #pragma unroll
            for (int tt = 0; tt < 4; ++tt) {
                const float lv = e[tt] * inv;
                ushort hh, ll; bfsplit(lv, hh, ll);
                if (!LAST) { Bh[(16 * tt + lo4) * 72 + l] = hh; Bl[(16 * tt + lo4) * 72 + l] = ll; }
                else       { Bh[l * 72 + 16 * tt + lo4] = hh; Bl[l * 72 + 16 * tt + lo4] = ll; }
            }
        }
        if (!LAST) scatter_tr(Ah, Al, r, c0, fq);
        else       scatter_tr(Ah, Al, r, c0, split16(rawY, 1.f));
        __syncthreads();

        if (!LAST) {
            f32x4 acc2[4] = {};
            f32x4 tacc = {};
            short8v onesb;
            #pragma unroll
            for (int e2 = 0; e2 < 8; ++e2) onesb[e2] = (lo4 == 0) ? (short)0x3F80 : (short)0;
            #pragma unroll
            for (int ks = 0; ks < 2; ++ks) {
                short8v ah = LD8(Bh, 16 * w + lo4, hi4 + 4 * ks);  // left^T rows
                short8v al = LD8(Bl, 16 * w + lo4, hi4 + 4 * ks);
                MFMA(tacc, ah, onesb); MFMA(tacc, al, onesb);
                #pragma unroll
                for (int tt = 0; tt < 4; ++tt) {
                    short8v bh = LD8(Ah, 16 * tt + lo4, hi4 + 4 * ks); // q^T rows
                    short8v bl = LD8(Al, 16 * tt + lo4, hi4 + 4 * ks);
                    MFMA(acc2[tt], ah, bh); MFMA(acc2[tt], ah, bl); MFMA(acc2[tt], al, bh);
                }
            }
            __syncthreads();
            #pragma unroll
            for (int rr = 0; rr < 4; ++rr) {
                const int kq = 16 * w + 4 * hi4 + rr;
                if (lo4 == 0) tauOut[((size_t)h * 64 + j) * 64 + kq] = tacc[rr];
                #pragma unroll
                for (int tt = 0; tt < 4; ++tt) OSB[kq * 68 + 16 * tt + lo4] = acc2[tt][rr];
            }
            __syncthreads();
            flush_f32(OSB, Gout + ((size_t)h * 64 + j) * 4096, tid);
        } else {
            f32x4 acc2[4] = {};
            #pragma unroll
            for (int ks = 0; ks < 2; ++ks) {
                short8v ah = LD8(Bh, 16 * w + lo4, hi4 + 4 * ks);  // left rows
                short8v al = LD8(Bl, 16 * w + lo4, hi4 + 4 * ks);
                #pragma unroll
                for (int tt = 0; tt < 4; ++tt) {
                    short8v bh = LD8(Ah, 16 * tt + lo4, hi4 + 4 * ks); // Y^T rows
                    short8v bl = LD8(Al, 16 * tt + lo4, hi4 + 4 * ks);
                    MFMA(acc2[tt], ah, bh); MFMA(acc2[tt], ah, bl); MFMA(acc2[tt], al, bh);
                }
            }
            __syncthreads();
            #pragma unroll
            for (int rr = 0; rr < 4; ++rr) {
                const int l = 16 * w + 4 * hi4 + rr;
                #pragma unroll
                for (int tt = 0; tt < 4; ++tt) OSB[l * 68 + 16 * tt + lo4] = acc2[tt][rr];
            }
            __syncthreads();
            #pragma unroll
            for (int q = 0; q < 4; ++q) {
                const int l = (tid >> 4) + 16 * q;
                const int v4 = (tid & 15) * 4;
                float4 vv = *(const float4*)(OSB + l * 68 + v4);
                *(float4*)(Zout + (size_t)h * HEADQ + (size_t)l * 4096 + (size_t)j * 64 + v4) = vv;
            }
        }
        __syncthreads();                                // LDS free for next tile
    }
}

} // namespace

extern "C" void kernel_launch(void* const* d_in, const int* in_sizes, int n_in,
                              void* d_out, int out_size, void* d_ws, size_t ws_size,
                              hipStream_t stream) {
    const float* Q = (const float*)d_in[0];
    const float* K = (const float*)d_in[1];
    const float* V = (const float*)d_in[2];
    float* out = (float*)d_out;

    char* ws = (char*)d_ws;
    const size_t MB = 1024 * 1024;
    float* G   = (float*)(ws);                  // 64 MiB (fallback: z staging)
    float* Hm  = (float*)(ws + 64 * MB);        // 64 MiB
    float* M   = (float*)(ws + 128 * MB);       //  1 MiB
    float* al  = (float*)(ws + 129 * MB);       //  1 MiB
    float* tau = (float*)(ws + 130 * MB);       //  1 MiB

    const bool bigws = ws_size >= (size_t)196 * MB;
    float* Ybuf = bigws ? (float*)(ws + 131 * MB) : out;
    float* Zdst = bigws ? out : G;

    dim3 blk(256), grid(1024);

    kmean_kernel<<<grid, blk, 0, stream>>>(Q, M);
    bc_kernel<1, 0><<<grid, blk, 0, stream>>>(M, K, nullptr, nullptr, Hm, al, nullptr);
    da_kernel<0>   <<<grid, blk, 0, stream>>>(Q, Hm, al, nullptr, G, tau, nullptr);
    bc_kernel<0, 0><<<grid, blk, 0, stream>>>(G, K, nullptr, tau, Hm, al, nullptr);
    da_kernel<0>   <<<grid, blk, 0, stream>>>(Q, Hm, al, nullptr, G, tau, nullptr);
    bc_kernel<0, 1><<<grid, blk, 0, stream>>>(G, K, V, tau, Hm, al, Ybuf);
    da_kernel<1>   <<<grid, blk, 0, stream>>>(Q, Hm, al, Ybuf, nullptr, nullptr, Zdst);
    if (!bigws)
        hipMemcpyAsync(d_out, G, MATF * sizeof(float), hipMemcpyDeviceToDevice, stream);
}

// Round 6
// 373.587 us; speedup vs baseline: 1.0969x; 1.0969x over previous
//
#include <hip/hip_runtime.h>

// SOBA-Monarch, B*H=64 heads, S=4096, D=64, nb=bs=64, pad=0, 3 steps.
// Round 6: R4 structure (grid 4096, 1 tile/WG) +
//  - intermediates G/Hm/Y as SPLIT bf16 hi/lo arrays (pure-copy staging)
//  - XOR-swizzled [64][64] ushort LDS tiles, 32 KiB total -> 5 WG/CU
// Layouts: G/Hm/Y: [h][?][tile 64x64] hi+lo bf16 | M [h][j][v] hi+lo
//          alpha [h][j][k] f32 (bc scatter-write, da contig read)
//          tau   [h][k][j] f32 (da scatter-write, bc contig read)

namespace {

typedef __attribute__((ext_vector_type(8))) short short8v;
typedef __attribute__((ext_vector_type(4))) float f32x4;

constexpr int HEADS = 64;
constexpr size_t HEADQ = 262144;                 // 4096*64 per head
constexpr size_t MATF  = (size_t)HEADS * 262144;

#define MFMA(ACC, A, B) ACC = __builtin_amdgcn_mfma_f32_16x16x32_bf16(A, B, ACC, 0, 0, 0)

__device__ __forceinline__ int swz(int row, int col) {
    return row * 64 + (((col >> 3) ^ (row & 7)) << 3) + (col & 7);
}
__device__ __forceinline__ short8v ldx(const ushort* a, int row, int chunk) {
    return *(const short8v*)(a + row * 64 + ((chunk ^ (row & 7)) << 3));
}

__device__ __forceinline__ float rmax16(float m) {
    m = fmaxf(m, __shfl_xor(m, 1));
    m = fmaxf(m, __shfl_xor(m, 2));
    m = fmaxf(m, __shfl_xor(m, 4));
    m = fmaxf(m, __shfl_xor(m, 8));
    return m;
}
__device__ __forceinline__ float rsum16(float s) {
    s += __shfl_xor(s, 1);
    s += __shfl_xor(s, 2);
    s += __shfl_xor(s, 4);
    s += __shfl_xor(s, 8);
    return s;
}

__device__ __forceinline__ void bfsplit(float x, ushort& h, ushort& l) {
    uint u = __float_as_uint(x);
    uint hi = (u + 0x7FFFu + ((u >> 16) & 1u)) & 0xFFFF0000u;
    h = (ushort)(hi >> 16);
    l = (ushort)(__float_as_uint(x - __uint_as_float(hi)) >> 16);
}

struct Frag16 { short8v h0, h1, l0, l1; };

// f32 global (16 elems at p) -> split regs
__device__ __forceinline__ Frag16 split_load(const float* __restrict__ p, float s) {
    Frag16 f;
    #pragma unroll
    for (int q = 0; q < 4; ++q) {
        float4 a = *(const float4*)(p + 4 * q);
        float v[4] = {a.x * s, a.y * s, a.z * s, a.w * s};
        #pragma unroll
        for (int e = 0; e < 4; ++e) {
            ushort hh, ll; bfsplit(v[e], hh, ll);
            const int i = 4 * q + e;
            if (i < 8) { f.h0[i] = (short)hh; f.l0[i] = (short)ll; }
            else       { f.h1[i - 8] = (short)hh; f.l1[i - 8] = (short)ll; }
        }
    }
    return f;
}
// split global (pre-split hi/lo arrays) -> regs (pure copy)
__device__ __forceinline__ Frag16 copy_load(const ushort* __restrict__ gh,
                                            const ushort* __restrict__ gl) {
    Frag16 f;
    f.h0 = *(const short8v*)(gh);     f.h1 = *(const short8v*)(gh + 8);
    f.l0 = *(const short8v*)(gl);     f.l1 = *(const short8v*)(gl + 8);
    return f;
}
__device__ __forceinline__ void store_rows(ushort* H, ushort* L, int r, int c0,
                                           const Frag16& f) {
    const int ch = c0 >> 3;
    const int o0 = r * 64 + ((ch ^ (r & 7)) << 3);
    const int o1 = r * 64 + (((ch + 1) ^ (r & 7)) << 3);
    *(short8v*)(H + o0) = f.h0; *(short8v*)(H + o1) = f.h1;
    *(short8v*)(L + o0) = f.l0; *(short8v*)(L + o1) = f.l1;
}
__device__ __forceinline__ void scatter_tr(ushort* H, ushort* L, int r, int c0,
                                           const Frag16& f) {
    #pragma unroll
    for (int e = 0; e < 8; ++e) {
        H[swz(c0 + e, r)] = (ushort)f.h0[e];
        L[swz(c0 + e, r)] = (ushort)f.l0[e];
    }
    #pragma unroll
    for (int e = 0; e < 8; ++e) {
        H[swz(c0 + 8 + e, r)] = (ushort)f.h1[e];
        L[swz(c0 + 8 + e, r)] = (ushort)f.l1[e];
    }
}

// flush linear ushort[4096] staging tile -> contiguous 8KB global
__device__ __forceinline__ void flush_u16(const ushort* OS, ushort* g, int tid) {
    *(short8v*)(g + tid * 16)     = *(const short8v*)(OS + tid * 16);
    *(short8v*)(g + tid * 16 + 8) = *(const short8v*)(OS + tid * 16 + 8);
}

__device__ __forceinline__ void mmstep(const ushort* AH, const ushort* AL,
                                       const ushort* BH, const ushort* BL,
                                       int w, int lo4, int hi4, f32x4 acc[4]) {
    #pragma unroll
    for (int ks = 0; ks < 2; ++ks) {
        short8v ah = ldx(AH, 16 * w + lo4, hi4 + 4 * ks);
        short8v al = ldx(AL, 16 * w + lo4, hi4 + 4 * ks);
        #pragma unroll
        for (int t = 0; t < 4; ++t) {
            short8v bh = ldx(BH, 16 * t + lo4, hi4 + 4 * ks);
            short8v bl = ldx(BL, 16 * t + lo4, hi4 + 4 * ks);
            MFMA(acc[t], ah, bh); MFMA(acc[t], ah, bl); MFMA(acc[t], al, bh);
        }
    }
}

// M[h][j][v] = (1/512) * sum_l Q[h][l*64+j][v], split hi/lo
__global__ __launch_bounds__(256) void kmean_kernel(const float* __restrict__ Q,
                                                    ushort* __restrict__ Mh,
                                                    ushort* __restrict__ Ml) {
    const int wg = blockIdx.x;                      // 1024 WGs
    const int h  = wg >> 4;
    const int j  = ((wg & 15) << 2) + (threadIdx.x >> 6);
    const int v  = threadIdx.x & 63;
    const float* base = Q + (size_t)h * HEADQ + (size_t)j * 64 + v;
    float acc = 0.f;
    #pragma unroll
    for (int l = 0; l < 64; ++l) acc += base[(size_t)l * 4096];
    ushort hh, ll; bfsplit(acc * (1.0f / 512.0f), hh, ll);
    Mh[((size_t)h * 64 + j) * 64 + v] = hh;
    Ml[((size_t)h * 64 + j) * 64 + v] = ll;
}

// One WG (256T) per (h,k).
// MM1: beta[j,i]=sum_v G[j,v]K[i,v]; right=softmax_i(beta/tau); alpha[j]=sum r log r
// MM2: Hm[j,v]=sum_i right[j,i]K[i,v];  LAST: Y[j,v]=sum_i right[j,i]V[i,v]
template<int FIRST, int LAST, int YSPLIT>
__global__ __launch_bounds__(256, 5) void bc_kernel(
    const ushort* __restrict__ Gsh,   // FIRST ? Mh : Gh   [h][j][k][v] (or [h][j][v])
    const ushort* __restrict__ Gsl,
    const float*  __restrict__ Kmat,
    const float*  __restrict__ Vmat,  // LAST only
    const float*  __restrict__ tauIn, // !FIRST, [h][k][j]
    ushort* __restrict__ Hmh,         // [h][k][j][v]
    ushort* __restrict__ Hml,
    float*  __restrict__ alphaOut,    // [h][j][k]
    ushort* __restrict__ Yh,          // LAST+YSPLIT, [h][k][j][v]
    ushort* __restrict__ Yl,
    float*  __restrict__ Yf)          // LAST+!YSPLIT, [h][k][j][v] f32
{
    __shared__ __align__(16) ushort SM[16384];     // 32768 B -> 5 WG/CU
    ushort* Ah = SM;          ushort* Al = SM + 4096;
    ushort* Bh = SM + 8192;   ushort* Bl = SM + 12288;

    const int wg = blockIdx.x, h = wg >> 6, k = wg & 63;
    const int tid = threadIdx.x, r = tid & 63, c0 = (tid >> 6) << 4;
    const int w = tid >> 6, lo4 = tid & 15, hi4 = (tid >> 4) & 3;

    { // stage G rows -> A (pure copy from split arrays)
        const size_t gb = FIRST ? (((size_t)h * 64 + r) * 64 + c0)
                                : (((size_t)h * 64 + r) * 4096 + (size_t)k * 64 + c0);
        store_rows(Ah, Al, r, c0, copy_load(Gsh + gb, Gsl + gb));
    }
    // stage K rows -> B, keep regs for K^T scatter
    Frag16 fk = split_load(Kmat + (size_t)h * HEADQ + (size_t)k * 4096 + r * 64 + c0, 1.f);
    store_rows(Bh, Bl, r, c0, fk);
    Frag16 fv;
    if (LAST)
        fv = split_load(Vmat + (size_t)h * HEADQ + (size_t)k * 4096 + r * 64 + c0, 1.f);
    float tvv[4];
    #pragma unroll
    for (int rr = 0; rr < 4; ++rr)
        tvv[rr] = FIRST ? 1.f : tauIn[((size_t)h * 64 + k) * 64 + 16 * w + 4 * hi4 + rr];
    __syncthreads();

    f32x4 acc[4] = {};
    mmstep(Ah, Al, Bh, Bl, w, lo4, hi4, acc);      // D[j,i]
    __syncthreads();

    // softmax over i; right -> A rows (swz); K^T -> B
    #pragma unroll
    for (int rr = 0; rr < 4; ++rr) {
        const int j = 16 * w + 4 * hi4 + rr;
        const bool tz = !(tvv[rr] > 1e-8f);
        const float tvi = tz ? 1.f : 1.f / tvv[rr];
        float lg[4];
        #pragma unroll
        for (int t = 0; t < 4; ++t) lg[t] = acc[t][rr] * tvi;
        float m = rmax16(fmaxf(fmaxf(lg[0], lg[1]), fmaxf(lg[2], lg[3])));
        float e[4], s = 0.f;
        #pragma unroll
        for (int t = 0; t < 4; ++t) { e[t] = __expf(lg[t] - m); s += e[t]; }
        s = rsum16(s);
        const float inv = 1.f / s;
        float ap = 0.f;
        #pragma unroll
        for (int t = 0; t < 4; ++t) {
            const float rv = tz ? (1.f / 64.f) : e[t] * inv;
            ap += (rv > 0.f) ? rv * __logf(rv) : 0.f;
            ushort hh, ll; bfsplit(rv, hh, ll);
            const int idx = swz(j, 16 * t + lo4);
            Ah[idx] = hh; Al[idx] = ll;
        }
        ap = rsum16(ap);
        if (lo4 == 0) alphaOut[((size_t)h * 64 + j) * 64 + k] = ap;
    }
    scatter_tr(Bh, Bl, r, c0, fk);                 // K^T over dead K rows
    __syncthreads();

    f32x4 acc2[4] = {};
    mmstep(Ah, Al, Bh, Bl, w, lo4, hi4, acc2);     // Hm: A=right, B=K^T
    f32x4 acc3[4] = {};
    if (LAST) {
        __syncthreads();
        scatter_tr(Bh, Bl, r, c0, fv);             // V^T over dead K^T
        __syncthreads();
        mmstep(Ah, Al, Bh, Bl, w, lo4, hi4, acc3); // Y: A=right, B=V^T
    }
    __syncthreads();

    // stage Hm split -> B (linear); LAST: Y -> A (split or f32)
    #pragma unroll
    for (int rr = 0; rr < 4; ++rr) {
        const int j = 16 * w + 4 * hi4 + rr;
        #pragma unroll
        for (int t = 0; t < 4; ++t) {
            ushort hh, ll; bfsplit(acc2[t][rr], hh, ll);
            Bh[j * 64 + 16 * t + lo4] = hh;
            Bl[j * 64 + 16 * t + lo4] = ll;
            if (LAST) {
                if (YSPLIT) {
                    ushort yh, yl; bfsplit(acc3[t][rr], yh, yl);
                    Ah[j * 64 + 16 * t + lo4] = yh;
                    Al[j * 64 + 16 * t + lo4] = yl;
                } else {
                    ((float*)Ah)[j * 64 + 16 * t + lo4] = acc3[t][rr];
                }
            }
        }
    }
    __syncthreads();
    const size_t ob = ((size_t)h * 64 + k) * 4096;
    flush_u16(Bh, Hmh + ob, tid);
    flush_u16(Bl, Hml + ob, tid);
    if (LAST) {
        if (YSPLIT) {
            flush_u16(Ah, Yh + ob, tid);
            flush_u16(Al, Yl + ob, tid);
        } else {
            const float* Zs = (const float*)Ah;
            #pragma unroll
            for (int q = 0; q < 4; ++q)
                *(float4*)(Yf + ob + tid * 16 + 4 * q) = *(const float4*)(Zs + tid * 16 + 4 * q);
        }
    }
}

// One WG per (h,j).
// MM1: beta2[l,k]=sum_v q[l,v]Hm[k,v]; left=softmax_k(beta2-alpha[k])
// !LAST: G[k,v]=sum_l left[l,k]q[l,v] (split out); tau[k] via ones-MFMA
//  LAST: Z[l,v]=sum_k left[l,k]Y[k,v]
template<int LAST, int YSPLIT>
__global__ __launch_bounds__(256, 5) void da_kernel(
    const float*  __restrict__ Q,
    const ushort* __restrict__ Hmh,   // [h][k][j][v]
    const ushort* __restrict__ Hml,
    const float*  __restrict__ alphaIn, // [h][j][k]
    const ushort* __restrict__ Yh,    // LAST+YSPLIT
    const ushort* __restrict__ Yl,
    const float*  __restrict__ Yf,    // LAST+!YSPLIT
    ushort* __restrict__ Goh,         // !LAST, [h][j][k][v]
    ushort* __restrict__ Gol,
    float*  __restrict__ tauOut,      // !LAST, [h][k][j]
    float*  __restrict__ Zout)        // LAST
{
    __shared__ __align__(16) ushort SM[16384];
    ushort* Ah = SM;          ushort* Al = SM + 4096;
    ushort* Bh = SM + 8192;   ushort* Bl = SM + 12288;

    const int wg = blockIdx.x, h = wg >> 6, j = wg & 63;
    const int tid = threadIdx.x, r = tid & 63, c0 = (tid >> 6) << 4;
    const int w = tid >> 6, lo4 = tid & 15, hi4 = (tid >> 4) & 3;

    // stage q (x0.125) -> A, keep regs for q^T
    Frag16 fq = split_load(Q + (size_t)h * HEADQ + (size_t)r * 4096 + (size_t)j * 64 + c0,
                           0.125f);
    store_rows(Ah, Al, r, c0, fq);
    { // stage Hm rows -> B (pure copy)
        const size_t hb = ((size_t)h * 64 + r) * 4096 + (size_t)j * 64 + c0;
        store_rows(Bh, Bl, r, c0, copy_load(Hmh + hb, Hml + hb));
    }
    Frag16 fy;
    if (LAST) {
        const size_t yb = ((size_t)h * 64 + r) * 4096 + (size_t)j * 64 + c0;
        if (YSPLIT) fy = copy_load(Yh + yb, Yl + yb);
        else        fy = split_load(Yf + yb, 1.f);
    }
    float av[4];
    #pragma unroll
    for (int t = 0; t < 4; ++t)
        av[t] = alphaIn[((size_t)h * 64 + j) * 64 + 16 * t + lo4];
    __syncthreads();

    f32x4 acc[4] = {};
    mmstep(Ah, Al, Bh, Bl, w, lo4, hi4, acc);      // D[l,k]
    __syncthreads();

    // left = softmax over k; left(^T) -> B; q^T / Y^T -> A
    #pragma unroll
    for (int rr = 0; rr < 4; ++rr) {
        const int l = 16 * w + 4 * hi4 + rr;
        float lg[4];
        #pragma unroll
        for (int t = 0; t < 4; ++t) lg[t] = acc[t][rr] - av[t];
        float m = rmax16(fmaxf(fmaxf(lg[0], lg[1]), fmaxf(lg[2], lg[3])));
        float e[4], s = 0.f;
        #pragma unroll
        for (int t = 0; t < 4; ++t) { e[t] = __expf(lg[t] - m); s += e[t]; }
        s = rsum16(s);
        const float inv = 1.f / s;
        #pragma unroll
        for (int t = 0; t < 4; ++t) {
            const float lv = e[t] * inv;
            ushort hh, ll; bfsplit(lv, hh, ll);
            const int idx = LAST ? swz(l, 16 * t + lo4) : swz(16 * t + lo4, l);
            Bh[idx] = hh; Bl[idx] = ll;
        }
    }
    if (!LAST) scatter_tr(Ah, Al, r, c0, fq);      // q^T over dead q rows
    else       scatter_tr(Ah, Al, r, c0, fy);      // Y^T over dead q rows
    __syncthreads();

    if (!LAST) {
        f32x4 acc2[4] = {};
        f32x4 tacc = {};
        short8v onesb;
        #pragma unroll
        for (int e2 = 0; e2 < 8; ++e2) onesb[e2] = (lo4 == 0) ? (short)0x3F80 : (short)0;
        #pragma unroll
        for (int ks = 0; ks < 2; ++ks) {
            short8v ah = ldx(Bh, 16 * w + lo4, hi4 + 4 * ks);   // left^T rows (k)
            short8v al = ldx(Bl, 16 * w + lo4, hi4 + 4 * ks);
            MFMA(tacc, ah, onesb); MFMA(tacc, al, onesb);
            #pragma unroll
            for (int t = 0; t < 4; ++t) {
                short8v bh = ldx(Ah, 16 * t + lo4, hi4 + 4 * ks); // q^T rows (v)
                short8v bl = ldx(Al, 16 * t + lo4, hi4 + 4 * ks);
                MFMA(acc2[t], ah, bh); MFMA(acc2[t], ah, bl); MFMA(acc2[t], al, bh);
            }
        }
        __syncthreads();
        #pragma unroll
        for (int rr = 0; rr < 4; ++rr) {            // stage G split -> B linear
            const int kq = 16 * w + 4 * hi4 + rr;
            if (lo4 == 0) tauOut[((size_t)h * 64 + kq) * 64 + j] = tacc[rr];
            #pragma unroll
            for (int t = 0; t < 4; ++t) {
                ushort hh, ll; bfsplit(acc2[t][rr], hh, ll);
                Bh[kq * 64 + 16 * t + lo4] = hh;
                Bl[kq * 64 + 16 * t + lo4] = ll;
            }
        }
        __syncthreads();
        const size_t ob = ((size_t)h * 64 + j) * 4096;
        flush_u16(Bh, Goh + ob, tid);
        flush_u16(Bl, Gol + ob, tid);
    } else {
        f32x4 acc2[4] = {};
        #pragma unroll
        for (int ks = 0; ks < 2; ++ks) {
            short8v ah = ldx(Bh, 16 * w + lo4, hi4 + 4 * ks);   // left rows (l)
            short8v al = ldx(Bl, 16 * w + lo4, hi4 + 4 * ks);
            #pragma unroll
            for (int t = 0; t < 4; ++t) {
                short8v bh = ldx(Ah, 16 * t + lo4, hi4 + 4 * ks); // Y^T rows (v)
                short8v bl = ldx(Al, 16 * t + lo4, hi4 + 4 * ks);
                MFMA(acc2[t], ah, bh); MFMA(acc2[t], ah, bl); MFMA(acc2[t], al, bh);
            }
        }
        __syncthreads();
        float* Zs = (float*)Ah;                     // 16 KB f32 staging over A
        #pragma unroll
        for (int rr = 0; rr < 4; ++rr) {
            const int l = 16 * w + 4 * hi4 + rr;
            #pragma unroll
            for (int t = 0; t < 4; ++t) Zs[l * 64 + 16 * t + lo4] = acc2[t][rr];
        }
        __syncthreads();
        #pragma unroll
        for (int q = 0; q < 4; ++q) {               // 256-B chunk per 16-lane group
            const int l = (tid >> 4) + 16 * q;
            const int v4 = (tid & 15) * 4;
            float4 vv = *(const float4*)(Zs + l * 64 + v4);
            *(float4*)(Zout + (size_t)h * HEADQ + (size_t)l * 4096 + (size_t)j * 64 + v4) = vv;
        }
    }
}

} // namespace

extern "C" void kernel_launch(void* const* d_in, const int* in_sizes, int n_in,
                              void* d_out, int out_size, void* d_ws, size_t ws_size,
                              hipStream_t stream) {
    const float* Q = (const float*)d_in[0];
    const float* K = (const float*)d_in[1];
    const float* V = (const float*)d_in[2];
    float* out = (float*)d_out;

    char* ws = (char*)d_ws;
    const size_t MB = 1024 * 1024;
    ushort* Gh  = (ushort*)(ws);                  // 32 MiB
    ushort* Gl  = (ushort*)(ws + 32 * MB);        // 32 MiB
    ushort* Hmh = (ushort*)(ws + 64 * MB);        // 32 MiB
    ushort* Hml = (ushort*)(ws + 96 * MB);        // 32 MiB
    ushort* Mh  = (ushort*)(ws + 128 * MB);       // 0.5 MiB
    ushort* Ml  = (ushort*)(ws + 128 * MB + 512 * 1024);
    float*  al  = (float*)(ws + 129 * MB);        // 1 MiB
    float*  tau = (float*)(ws + 130 * MB);        // 1 MiB

    const bool bigws = ws_size >= (size_t)195 * MB;
    ushort* Yh = bigws ? (ushort*)(ws + 131 * MB) : nullptr;   // 32 MiB
    ushort* Yl = bigws ? (ushort*)(ws + 163 * MB) : nullptr;   // 32 MiB
    float*  Yf = bigws ? nullptr : out;                        // f32 Y in d_out
    float*  Zdst = bigws ? out : (float*)ws;                   // !bigws: Z over G region

    dim3 blk(256), grid(HEADS * 64);

    kmean_kernel<<<dim3(1024), blk, 0, stream>>>(Q, Mh, Ml);
    bc_kernel<1, 0, 0><<<grid, blk, 0, stream>>>(Mh, Ml, K, nullptr, nullptr,
                                                 Hmh, Hml, al, nullptr, nullptr, nullptr);
    da_kernel<0, 0>   <<<grid, blk, 0, stream>>>(Q, Hmh, Hml, al, nullptr, nullptr, nullptr,
                                                 Gh, Gl, tau, nullptr);
    bc_kernel<0, 0, 0><<<grid, blk, 0, stream>>>(Gh, Gl, K, nullptr, tau,
                                                 Hmh, Hml, al, nullptr, nullptr, nullptr);
    da_kernel<0, 0>   <<<grid, blk, 0, stream>>>(Q, Hmh, Hml, al, nullptr, nullptr, nullptr,
                                                 Gh, Gl, tau, nullptr);
    if (bigws) {
        bc_kernel<0, 1, 1><<<grid, blk, 0, stream>>>(Gh, Gl, K, V, tau,
                                                     Hmh, Hml, al, Yh, Yl, nullptr);
        da_kernel<1, 1>   <<<grid, blk, 0, stream>>>(Q, Hmh, Hml, al, Yh, Yl, nullptr,
                                                     nullptr, nullptr, nullptr, Zdst);
    } else {
        bc_kernel<0, 1, 0><<<grid, blk, 0, stream>>>(Gh, Gl, K, V, tau,
                                                     Hmh, Hml, al, nullptr, nullptr, Yf);
        da_kernel<1, 0>   <<<grid, blk, 0, stream>>>(Q, Hmh, Hml, al, nullptr, nullptr, Yf,
                                                     nullptr, nullptr, nullptr, Zdst);
        hipMemcpyAsync(d_out, Zdst, MATF * sizeof(float), hipMemcpyDeviceToDevice, stream);
    }
}

// Round 7
// 328.865 us; speedup vs baseline: 1.2460x; 1.1360x over previous
//
#include <hip/hip_runtime.h>

// SOBA-Monarch, B*H=64 heads, S=4096, D=64, nb=bs=64, pad=0, 3 steps.
// Round 7 = R4 structure (grid 4096, 1 tile/WG, pad-72 LDS, (256,4)) +
//   packed-u32 (hi|lo bf16) intermediates (cheap unpack staging, full-line writes)
//   + direct global stores from accumulators (no output staging, fewer barriers).
// Layouts: G [h][j][k][v] u32 | Hm,Y [h][k][j][v] u32 | M [h][j][v] u32
//          alpha [h][k][j] f32 | tau [h][j][k] f32

namespace {

typedef __attribute__((ext_vector_type(8))) short short8v;
typedef __attribute__((ext_vector_type(4))) float f32x4;

constexpr int HEADS = 64;
constexpr size_t HEADQ = 262144;                 // 4096*64 per head
constexpr size_t MATF  = (size_t)HEADS * 262144;

#define MFMA(ACC, A, B) ACC = __builtin_amdgcn_mfma_f32_16x16x32_bf16(A, B, ACC, 0, 0, 0)
#define LD8(arr, row, g8) (*(const short8v*)((arr) + (row) * 72 + (g8) * 8))

__device__ __forceinline__ float rmax16(float m) {
    m = fmaxf(m, __shfl_xor(m, 1));
    m = fmaxf(m, __shfl_xor(m, 2));
    m = fmaxf(m, __shfl_xor(m, 4));
    m = fmaxf(m, __shfl_xor(m, 8));
    return m;
}
__device__ __forceinline__ float rsum16(float s) {
    s += __shfl_xor(s, 1);
    s += __shfl_xor(s, 2);
    s += __shfl_xor(s, 4);
    s += __shfl_xor(s, 8);
    return s;
}

__device__ __forceinline__ void bfsplit(float x, ushort& h, ushort& l) {
    uint u = __float_as_uint(x);
    uint hi = (u + 0x7FFFu + ((u >> 16) & 1u)) & 0xFFFF0000u;
    h = (ushort)(hi >> 16);
    l = (ushort)(__float_as_uint(x - __uint_as_float(hi)) >> 16);
}
__device__ __forceinline__ uint packbf(float x) {
    uint u = __float_as_uint(x);
    uint hi = (u + 0x7FFFu + ((u >> 16) & 1u)) & 0xFFFF0000u;
    return hi | (__float_as_uint(x - __uint_as_float(hi)) >> 16);
}

struct Frag16 { short8v h0, h1, l0, l1; };

// f32 global (16 elems) -> split regs (6 ops/elem, inputs only)
__device__ __forceinline__ Frag16 split_load(const float* __restrict__ p, float s) {
    Frag16 f;
    #pragma unroll
    for (int q = 0; q < 4; ++q) {
        float4 a = *(const float4*)(p + 4 * q);
        float v[4] = {a.x * s, a.y * s, a.z * s, a.w * s};
        #pragma unroll
        for (int e = 0; e < 4; ++e) {
            ushort hh, ll; bfsplit(v[e], hh, ll);
            const int i = 4 * q + e;
            if (i < 8) { f.h0[i] = (short)hh; f.l0[i] = (short)ll; }
            else       { f.h1[i - 8] = (short)hh; f.l1[i - 8] = (short)ll; }
        }
    }
    return f;
}
// packed-u32 global -> split regs (2 ops/elem)
__device__ __forceinline__ Frag16 unpack_load(const uint* __restrict__ p) {
    Frag16 f;
    #pragma unroll
    for (int q = 0; q < 2; ++q) {
        uint4 a = *(const uint4*)(p + 8 * q);
        uint4 b = *(const uint4*)(p + 8 * q + 4);
        uint vv[8] = {a.x, a.y, a.z, a.w, b.x, b.y, b.z, b.w};
        short8v h, l;
        #pragma unroll
        for (int e = 0; e < 8; ++e) {
            h[e] = (short)(vv[e] >> 16);
            l[e] = (short)(vv[e] & 0xFFFFu);
        }
        if (q == 0) { f.h0 = h; f.l0 = l; } else { f.h1 = h; f.l1 = l; }
    }
    return f;
}
__device__ __forceinline__ void store_rows(ushort* H, ushort* L, int r, int c0,
                                           const Frag16& f) {
    *(short8v*)(H + r * 72 + c0)     = f.h0;
    *(short8v*)(H + r * 72 + c0 + 8) = f.h1;
    *(short8v*)(L + r * 72 + c0)     = f.l0;
    *(short8v*)(L + r * 72 + c0 + 8) = f.l1;
}
__device__ __forceinline__ void scatter_tr(ushort* H, ushort* L, int r, int c0,
                                           const Frag16& f) {
    #pragma unroll
    for (int e = 0; e < 8; ++e) {
        H[(c0 + e) * 72 + r] = (ushort)f.h0[e];
        L[(c0 + e) * 72 + r] = (ushort)f.l0[e];
    }
    #pragma unroll
    for (int e = 0; e < 8; ++e) {
        H[(c0 + 8 + e) * 72 + r] = (ushort)f.h1[e];
        L[(c0 + 8 + e) * 72 + r] = (ushort)f.l1[e];
    }
}

__device__ __forceinline__ void mmstep(const ushort* AH, const ushort* AL,
                                       const ushort* BH, const ushort* BL,
                                       int w, int lo4, int hi4, f32x4 acc[4]) {
    #pragma unroll
    for (int ks = 0; ks < 2; ++ks) {
        short8v ah = LD8(AH, 16 * w + lo4, hi4 + 4 * ks);
        short8v al = LD8(AL, 16 * w + lo4, hi4 + 4 * ks);
        #pragma unroll
        for (int t = 0; t < 4; ++t) {
            short8v bh = LD8(BH, 16 * t + lo4, hi4 + 4 * ks);
            short8v bl = LD8(BL, 16 * t + lo4, hi4 + 4 * ks);
            MFMA(acc[t], ah, bh); MFMA(acc[t], ah, bl); MFMA(acc[t], al, bh);
        }
    }
}

// M[h][j][v] = packbf( (1/512) * sum_l Q[h][l*64+j][v] )
__global__ __launch_bounds__(256) void kmean_kernel(const float* __restrict__ Q,
                                                    uint* __restrict__ M) {
    const int wg = blockIdx.x;                      // 1024 WGs
    const int h  = wg >> 4;
    const int j  = ((wg & 15) << 2) + (threadIdx.x >> 6);
    const int v  = threadIdx.x & 63;
    const float* base = Q + (size_t)h * HEADQ + (size_t)j * 64 + v;
    float acc = 0.f;
    #pragma unroll
    for (int l = 0; l < 64; ++l) acc += base[(size_t)l * 4096];
    M[((size_t)h * 64 + j) * 64 + v] = packbf(acc * (1.0f / 512.0f));
}

// One WG (256T) per (h,k).
// MM1: beta[j,i]=sum_v G[j,v]K[i,v]; right=softmax_i(beta/tau); alpha[j]=sum r log r
// MM2: Hm[j,v]=sum_i right[j,i]K[i,v];  LAST: Y[j,v]=sum_i right[j,i]V[i,v]
template<int FIRST, int LAST>
__global__ __launch_bounds__(256, 4) void bc_kernel(
    const uint*  __restrict__ Gsrc,   // FIRST ? M[h][j][v] : G[h][j][k][v]
    const float* __restrict__ Kmat,
    const float* __restrict__ Vmat,   // LAST only
    const float* __restrict__ tauIn,  // !FIRST, [h][j][k]
    uint*  __restrict__ HmOut,        // [h][k][j][v] packed
    float* __restrict__ alphaOut,     // [h][k][j]
    uint*  __restrict__ Yout)         // LAST only, [h][k][j][v] packed
{
    __shared__ __align__(16) ushort SM[18432];     // 36864 B -> 4 WG/CU
    ushort* Ah = SM;          ushort* Al = SM + 4608;
    ushort* Bh = SM + 9216;   ushort* Bl = SM + 13824;

    const int wg = blockIdx.x, h = wg >> 6, k = wg & 63;
    const int tid = threadIdx.x, r = tid & 63, c0 = (tid >> 6) << 4;
    const int w = tid >> 6, lo4 = tid & 15, hi4 = (tid >> 4) & 3;

    { // stage G rows -> A (cheap unpack)
        const uint* gp = FIRST ? Gsrc + ((size_t)h * 64 + r) * 64 + c0
                               : Gsrc + ((size_t)h * 64 + r) * 4096 + (size_t)k * 64 + c0;
        store_rows(Ah, Al, r, c0, unpack_load(gp));
    }
    // stage K rows -> B, keep regs for K^T scatter
    Frag16 fk = split_load(Kmat + (size_t)h * HEADQ + (size_t)k * 4096 + r * 64 + c0, 1.f);
    store_rows(Bh, Bl, r, c0, fk);
    Frag16 fv;
    if (LAST)
        fv = split_load(Vmat + (size_t)h * HEADQ + (size_t)k * 4096 + r * 64 + c0, 1.f);
    float tvv[4];
    #pragma unroll
    for (int rr = 0; rr < 4; ++rr)
        tvv[rr] = FIRST ? 1.f : tauIn[((size_t)h * 64 + 16 * w + 4 * hi4 + rr) * 64 + k];
    __syncthreads();

    f32x4 acc[4] = {};
    mmstep(Ah, Al, Bh, Bl, w, lo4, hi4, acc);      // D[j,i]
    __syncthreads();

    // softmax over i; right -> A rows; K^T -> B
    #pragma unroll
    for (int rr = 0; rr < 4; ++rr) {
        const int j = 16 * w + 4 * hi4 + rr;
        const bool tz = !(tvv[rr] > 1e-8f);
        const float tvi = tz ? 1.f : 1.f / tvv[rr];
        float lg[4];
        #pragma unroll
        for (int t = 0; t < 4; ++t) lg[t] = acc[t][rr] * tvi;
        float m = rmax16(fmaxf(fmaxf(lg[0], lg[1]), fmaxf(lg[2], lg[3])));
        float e[4], s = 0.f;
        #pragma unroll
        for (int t = 0; t < 4; ++t) { e[t] = __expf(lg[t] - m); s += e[t]; }
        s = rsum16(s);
        const float inv = 1.f / s;
        float ap = 0.f;
        #pragma unroll
        for (int t = 0; t < 4; ++t) {
            const float rv = tz ? (1.f / 64.f) : e[t] * inv;
            ap += (rv > 0.f) ? rv * __logf(rv) : 0.f;
            ushort hh, ll; bfsplit(rv, hh, ll);
            Ah[j * 72 + 16 * t + lo4] = hh;
            Al[j * 72 + 16 * t + lo4] = ll;
        }
        ap = rsum16(ap);
        if (lo4 == 0) alphaOut[((size_t)h * 64 + k) * 64 + j] = ap;
    }
    scatter_tr(Bh, Bl, r, c0, fk);                 // K^T over dead K rows
    __syncthreads();

    f32x4 acc2[4] = {};
    mmstep(Ah, Al, Bh, Bl, w, lo4, hi4, acc2);     // Hm: A=right, B=K^T
    f32x4 acc3[4] = {};
    if (LAST) {
        __syncthreads();
        scatter_tr(Bh, Bl, r, c0, fv);             // V^T over dead K^T
        __syncthreads();
        mmstep(Ah, Al, Bh, Bl, w, lo4, hi4, acc3); // Y: A=right, B=V^T
    }

    // direct packed stores (64B line per 16-lane group)
    #pragma unroll
    for (int rr = 0; rr < 4; ++rr) {
        const int j = 16 * w + 4 * hi4 + rr;
        const size_t ob = ((size_t)h * 64 + k) * 4096 + (size_t)j * 64;
        #pragma unroll
        for (int t = 0; t < 4; ++t) {
            HmOut[ob + 16 * t + lo4] = packbf(acc2[t][rr]);
            if (LAST) Yout[ob + 16 * t + lo4] = packbf(acc3[t][rr]);
        }
    }
}

// One WG per (h,j).
// MM1: beta2[l,k]=sum_v q[l,v]Hm[k,v]; left=softmax_k(beta2-alpha[k])
// !LAST: G[k,v]=sum_l left[l,k]q[l,v] (packed); tau[k] via ones-MFMA
//  LAST: Z[l,v]=sum_k left[l,k]Y[k,v] (f32)
template<int LAST>
__global__ __launch_bounds__(256, 4) void da_kernel(
    const float* __restrict__ Q,
    const uint*  __restrict__ HmIn,   // [h][k][j][v] packed
    const float* __restrict__ alphaIn,// [h][k][j]
    const uint*  __restrict__ Yin,    // LAST only, packed
    uint*  __restrict__ Gout,         // !LAST, [h][j][k][v] packed
    float* __restrict__ tauOut,       // !LAST, [h][j][k]
    float* __restrict__ Zout)         // LAST
{
    __shared__ __align__(16) ushort SM[18432];
    ushort* Ah = SM;          ushort* Al = SM + 4608;
    ushort* Bh = SM + 9216;   ushort* Bl = SM + 13824;

    const int wg = blockIdx.x, h = wg >> 6, j = wg & 63;
    const int tid = threadIdx.x, r = tid & 63, c0 = (tid >> 6) << 4;
    const int w = tid >> 6, lo4 = tid & 15, hi4 = (tid >> 4) & 3;

    // stage q (x0.125) -> A, keep regs for q^T
    Frag16 fq = split_load(Q + (size_t)h * HEADQ + (size_t)r * 4096 + (size_t)j * 64 + c0,
                           0.125f);
    store_rows(Ah, Al, r, c0, fq);
    { // stage Hm rows -> B (cheap unpack)
        store_rows(Bh, Bl, r, c0,
                   unpack_load(HmIn + ((size_t)h * 64 + r) * 4096 + (size_t)j * 64 + c0));
    }
    Frag16 fy;
    if (LAST)
        fy = unpack_load(Yin + ((size_t)h * 64 + r) * 4096 + (size_t)j * 64 + c0);
    float av[4];
    #pragma unroll
    for (int t = 0; t < 4; ++t)
        av[t] = alphaIn[((size_t)h * 64 + 16 * t + lo4) * 64 + j];
    __syncthreads();

    f32x4 acc[4] = {};
    mmstep(Ah, Al, Bh, Bl, w, lo4, hi4, acc);      // D[l,k]
    __syncthreads();

    // left = softmax over k; left(^T) -> B; q^T / Y^T -> A
    #pragma unroll
    for (int rr = 0; rr < 4; ++rr) {
        const int l = 16 * w + 4 * hi4 + rr;
        float lg[4];
        #pragma unroll
        for (int t = 0; t < 4; ++t) lg[t] = acc[t][rr] - av[t];
        float m = rmax16(fmaxf(fmaxf(lg[0], lg[1]), fmaxf(lg[2], lg[3])));
        float e[4], s = 0.f;
        #pragma unroll
        for (int t = 0; t < 4; ++t) { e[t] = __expf(lg[t] - m); s += e[t]; }
        s = rsum16(s);
        const float inv = 1.f / s;
        #pragma unroll
        for (int t = 0; t < 4; ++t) {
            const float lv = e[t] * inv;
            ushort hh, ll; bfsplit(lv, hh, ll);
            if (!LAST) { Bh[(16 * t + lo4) * 72 + l] = hh; Bl[(16 * t + lo4) * 72 + l] = ll; }
            else       { Bh[l * 72 + 16 * t + lo4] = hh; Bl[l * 72 + 16 * t + lo4] = ll; }
        }
    }
    if (!LAST) scatter_tr(Ah, Al, r, c0, fq);      // q^T over dead q rows
    else       scatter_tr(Ah, Al, r, c0, fy);      // Y^T over dead q rows
    __syncthreads();

    if (!LAST) {
        f32x4 acc2[4] = {};
        f32x4 tacc = {};
        short8v onesb;
        #pragma unroll
        for (int e2 = 0; e2 < 8; ++e2) onesb[e2] = (lo4 == 0) ? (short)0x3F80 : (short)0;
        #pragma unroll
        for (int ks = 0; ks < 2; ++ks) {
            short8v ah = LD8(Bh, 16 * w + lo4, hi4 + 4 * ks);   // left^T rows (k)
            short8v al = LD8(Bl, 16 * w + lo4, hi4 + 4 * ks);
            MFMA(tacc, ah, onesb); MFMA(tacc, al, onesb);
            #pragma unroll
            for (int t = 0; t < 4; ++t) {
                short8v bh = LD8(Ah, 16 * t + lo4, hi4 + 4 * ks); // q^T rows (v)
                short8v bl = LD8(Al, 16 * t + lo4, hi4 + 4 * ks);
                MFMA(acc2[t], ah, bh); MFMA(acc2[t], ah, bl); MFMA(acc2[t], al, bh);
            }
        }
        #pragma unroll
        for (int rr = 0; rr < 4; ++rr) {           // direct packed stores
            const int kq = 16 * w + 4 * hi4 + rr;
            if (lo4 == 0) tauOut[((size_t)h * 64 + j) * 64 + kq] = tacc[rr];
            const size_t gb = ((size_t)h * 64 + j) * 4096 + (size_t)kq * 64;
            #pragma unroll
            for (int t = 0; t < 4; ++t) Gout[gb + 16 * t + lo4] = packbf(acc2[t][rr]);
        }
    } else {
        f32x4 acc2[4] = {};
        #pragma unroll
        for (int ks = 0; ks < 2; ++ks) {
            short8v ah = LD8(Bh, 16 * w + lo4, hi4 + 4 * ks);   // left rows (l)
            short8v al = LD8(Bl, 16 * w + lo4, hi4 + 4 * ks);
            #pragma unroll
            for (int t = 0; t < 4; ++t) {
                short8v bh = LD8(Ah, 16 * t + lo4, hi4 + 4 * ks); // Y^T rows (v)
                short8v bl = LD8(Al, 16 * t + lo4, hi4 + 4 * ks);
                MFMA(acc2[t], ah, bh); MFMA(acc2[t], ah, bl); MFMA(acc2[t], al, bh);
            }
        }
        #pragma unroll
        for (int rr = 0; rr < 4; ++rr) {           // direct f32 stores (64B/group)
            const int l = 16 * w + 4 * hi4 + rr;
            const size_t zb = (size_t)h * HEADQ + (size_t)l * 4096 + (size_t)j * 64;
            #pragma unroll
            for (int t = 0; t < 4; ++t) Zout[zb + 16 * t + lo4] = acc2[t][rr];
        }
    }
}

} // namespace

extern "C" void kernel_launch(void* const* d_in, const int* in_sizes, int n_in,
                              void* d_out, int out_size, void* d_ws, size_t ws_size,
                              hipStream_t stream) {
    const float* Q = (const float*)d_in[0];
    const float* K = (const float*)d_in[1];
    const float* V = (const float*)d_in[2];
    float* out = (float*)d_out;

    char* ws = (char*)d_ws;
    const size_t MB = 1024 * 1024;
    uint*  G   = (uint*)(ws);                   // 64 MiB packed (fallback: z staging)
    uint*  Hm  = (uint*)(ws + 64 * MB);         // 64 MiB packed
    uint*  M   = (uint*)(ws + 128 * MB);        //  1 MiB packed
    float* al  = (float*)(ws + 129 * MB);       //  1 MiB
    float* tau = (float*)(ws + 130 * MB);       //  1 MiB

    const bool bigws = ws_size >= (size_t)195 * MB;
    uint*  Ybuf = bigws ? (uint*)(ws + 131 * MB) : (uint*)out;  // packed Y staging
    float* Zdst = bigws ? out : (float*)G;

    dim3 blk(256), grid(HEADS * 64);

    kmean_kernel<<<dim3(1024), blk, 0, stream>>>(Q, M);
    bc_kernel<1, 0><<<grid, blk, 0, stream>>>(M, K, nullptr, nullptr, Hm, al, nullptr);
    da_kernel<0>   <<<grid, blk, 0, stream>>>(Q, Hm, al, nullptr, G, tau, nullptr);
    bc_kernel<0, 0><<<grid, blk, 0, stream>>>(G, K, nullptr, tau, Hm, al, nullptr);
    da_kernel<0>   <<<grid, blk, 0, stream>>>(Q, Hm, al, nullptr, G, tau, nullptr);
    bc_kernel<0, 1><<<grid, blk, 0, stream>>>(G, K, V, tau, Hm, al, Ybuf);
    da_kernel<1>   <<<grid, blk, 0, stream>>>(Q, Hm, al, Ybuf, nullptr, nullptr, Zdst);
    if (!bigws)
        hipMemcpyAsync(d_out, Zdst, MATF * sizeof(float), hipMemcpyDeviceToDevice, stream);
}